// Round 11
// baseline (81.004 us; speedup 1.0000x reference)
//
#include <hip/hip_runtime.h>

#define M_NODES 50000
#define KDIM    256
#define NDIM    96
#define NEDGE   800000
#define BM      64     // gemm rows per block
#define GEMM_BLKS 782  // ceil(50000/64)
#define NPB     64     // nodes per bucket
#define NBUCK   782    // ceil(50000/64)
#define CAPB    1536   // per-bucket edge capacity (mean 1023, sigma 32 -> +16s)
#define EPB     2048   // edges per scatter block
#define NBLK_SC 391    // ceil(800000/2048)

typedef short bf16x8 __attribute__((ext_vector_type(8)));   // 8 bf16 (4 VGPRs)
typedef float f32x4  __attribute__((ext_vector_type(4)));

// round-to-nearest-even f32 -> bf16 (as u16)
__device__ inline unsigned short f2bf(float x) {
    unsigned u = __float_as_uint(x);
    u = (u + 0x7fffu + ((u >> 16) & 1u)) >> 16;
    return (unsigned short)u;
}
__device__ inline unsigned pack2bf(float x, float y) {
    return (unsigned)f2bf(x) | ((unsigned)f2bf(y) << 16);
}

// -------- Kernel 0: Wt[n][k] = bf16(W[k][n]); block 0 inits cursors ----
__global__ __launch_bounds__(256) void prep_w_kernel(
    const float* __restrict__ w, unsigned short* __restrict__ wt,
    int* __restrict__ gcursor)
{
    if (blockIdx.x == 0)
        for (int i = threadIdx.x; i < NBUCK; i += 256)
            gcursor[i] = i * CAPB;
    int i = blockIdx.x * 256 + threadIdx.x;   // over 96*256
    if (i < KDIM * NDIM) {
        int n = i >> 8;        // 0..95
        int k = i & 255;       // 0..255
        wt[i] = f2bf(w[(size_t)k * NDIM + n]);
    }
}

// -------- Kernel 1 (fat): gemm blocks [0,782) + scatter [782,1173) -----
// GEMM path: NO LDS. A: lane's full 256B h-slice prefetched into 16
//   float4 regs up front (one L3 round-trip). B: 16B/lane direct from
//   wt (global); per instr = 16 rows x 64B coalesced, L1-warm (48KB set).
// SCATTER path: bucket=dst>>6; LDS count -> chunk reserve -> packed write.
__global__ __launch_bounds__(256) void fused_gemm_scatter_kernel(
    const float* __restrict__ h, const float* __restrict__ norm,
    const unsigned short* __restrict__ wt, unsigned short* __restrict__ hwb,
    const int* __restrict__ src, const int* __restrict__ dst,
    int* __restrict__ gcursor, unsigned* __restrict__ binned)
{
    __shared__ int s_cnt[NBUCK];    // scatter path only (6.3 KB total)
    __shared__ int s_base[NBUCK];

    const int tid = threadIdx.x;

    if (blockIdx.x < GEMM_BLKS) {
        // ---------------- GEMM path ----------------
        const int lane = tid & 63;
        const int wv   = tid >> 6;                   // 0..3
        const int row0 = blockIdx.x * BM;
        const int ar   = wv * 16 + (lane & 15);      // A row within tile
        const int kg   = lane >> 4;                  // 0..3 (8-elem k-group)
        int arow = row0 + ar;
        if (arow >= M_NODES) arow = M_NODES - 1;     // clamp; results discarded
        const float* __restrict__ hrow = h + (size_t)arow * KDIM + kg * 8;

        // prefetch lane's entire A slice: 16 independent float4 loads
        float4 hr[16];
#pragma unroll
        for (int s = 0; s < 8; ++s) {
            hr[2 * s]     = *reinterpret_cast<const float4*>(hrow + s * 32);
            hr[2 * s + 1] = *reinterpret_cast<const float4*>(hrow + s * 32 + 4);
        }

        // B base for this lane: row (lane&15), k-chunk kg
        const unsigned short* __restrict__ wb =
            wt + (size_t)(lane & 15) * KDIM + kg * 8;

        f32x4 acc[6];
#pragma unroll
        for (int f = 0; f < 6; ++f) acc[f] = (f32x4){0.f, 0.f, 0.f, 0.f};

#pragma unroll
        for (int s = 0; s < 8; ++s) {
            union { bf16x8 v; unsigned u[4]; } a;
            float4 p = hr[2 * s], q = hr[2 * s + 1];
            a.u[0] = pack2bf(p.x, p.y);
            a.u[1] = pack2bf(p.z, p.w);
            a.u[2] = pack2bf(q.x, q.y);
            a.u[3] = pack2bf(q.z, q.w);
#pragma unroll
            for (int f = 0; f < 6; ++f) {
                bf16x8 b = *reinterpret_cast<const bf16x8*>(
                    wb + (size_t)f * 16 * KDIM + s * 32);
                acc[f] = __builtin_amdgcn_mfma_f32_16x16x32_bf16(a.v, b, acc[f], 0, 0, 0);
            }
        }

        // epilogue: C/D layout col=lane&15, row=(lane>>4)*4+reg
        const int crow = wv * 16 + (lane >> 4) * 4;
        const int ccol = lane & 15;
#pragma unroll
        for (int r = 0; r < 4; ++r) {
            int row = row0 + crow + r;
            if (row < M_NODES) {
                float nv = norm[row];
#pragma unroll
                for (int f = 0; f < 6; ++f)
                    hwb[(size_t)row * NDIM + f * 16 + ccol] = f2bf(acc[f][r] * nv);
            }
        }
    } else {
        // ---------------- SCATTER path ----------------
        const int blk = blockIdx.x - GEMM_BLKS;
        const int e0 = blk * EPB;
        const int e1 = (e0 + EPB < NEDGE) ? e0 + EPB : NEDGE;

        for (int i = tid; i < NBUCK; i += 256) s_cnt[i] = 0;
        __syncthreads();
        for (int e = e0 + tid; e < e1; e += 256)
            atomicAdd(&s_cnt[dst[e] >> 6], 1);
        __syncthreads();
        for (int i = tid; i < NBUCK; i += 256) {
            int c = s_cnt[i];
            s_base[i] = c ? atomicAdd(&gcursor[i], c) : 0;
        }
        __syncthreads();
        for (int i = tid; i < NBUCK; i += 256) s_cnt[i] = 0;  // reuse as cursor
        __syncthreads();
        for (int e = e0 + tid; e < e1; e += 256) {
            int d = dst[e];
            int b = d >> 6;
            int pos = s_base[b] + atomicAdd(&s_cnt[b], 1);
            if (pos < (b + 1) * CAPB)                          // overflow guard
                binned[pos] = ((unsigned)(d & 63) << 16) | (unsigned)src[e];
        }
    }
}

// -------- Kernel 2: fused per-bucket CSR build + segment sum + relu ----
#define ACCV(A, v)                                     \
    A[0] += __uint_as_float((v).x << 16);              \
    A[1] += __uint_as_float((v).x & 0xffff0000u);      \
    A[2] += __uint_as_float((v).y << 16);              \
    A[3] += __uint_as_float((v).y & 0xffff0000u);      \
    A[4] += __uint_as_float((v).z << 16);              \
    A[5] += __uint_as_float((v).z & 0xffff0000u);      \
    A[6] += __uint_as_float((v).w << 16);              \
    A[7] += __uint_as_float((v).w & 0xffff0000u);

__global__ __launch_bounds__(256) void csr_agg_kernel(
    const unsigned* __restrict__ binned, const int* __restrict__ gcursor,
    const unsigned short* __restrict__ hwb, const float* __restrict__ norm,
    float* __restrict__ out)
{
    __shared__ unsigned eL[CAPB];          // raw packed edges (6 KB)
    __shared__ unsigned short oL[CAPB];    // node-ordered src ids (3 KB)
    __shared__ int cnt[NPB];               // histogram / cursor / end
    __shared__ int pfxE[NPB];              // exclusive start

    const int b  = blockIdx.x;
    const int t  = threadIdx.x;
    const int e0 = b * CAPB;
    int cntE = gcursor[b] - e0;
    if (cntE > CAPB) cntE = CAPB;

    for (int i = t; i < cntE; i += 256) eL[i] = binned[e0 + i];
    if (t < NPB) cnt[t] = 0;
    __syncthreads();
    for (int i = t; i < cntE; i += 256)
        atomicAdd(&cnt[(eL[i] >> 16) & 63], 1);
    __syncthreads();
    if (t < NPB) {                         // wave-0 barrier-free 64-wide scan
        int v = cnt[t];
        int x = v;
#pragma unroll
        for (int st = 1; st < 64; st <<= 1) {
            int o = __shfl_up(x, st, 64);
            if (t >= st) x += o;
        }
        int ex = x - v;                    // exclusive
        pfxE[t] = ex;
        cnt[t]  = ex;                      // cursor
    }
    __syncthreads();
    for (int i = t; i < cntE; i += 256) {
        unsigned v = eL[i];
        int d = (v >> 16) & 63;
        int p = atomicAdd(&cnt[d], 1);
        oL[p] = (unsigned short)(v & 0xffffu);
    }
    __syncthreads();
    // cnt[node] == segment end; pfxE[node] == segment start.

    // aggregate: 64 nodes x 12 channel-groups = 768 units, 3 passes
#pragma unroll
    for (int pass = 0; pass < 3; ++pass) {
        const int u     = pass * 256 + t;
        const int node  = u / 12;
        const int c8    = u - node * 12;       // channels c8*8 .. +7
        const int gnode = b * NPB + node;
        if (gnode < M_NODES) {
            const int s0 = pfxE[node];
            const int s1 = cnt[node];
            float acc[8]  = {0.f, 0.f, 0.f, 0.f, 0.f, 0.f, 0.f, 0.f};
            float acc2[8] = {0.f, 0.f, 0.f, 0.f, 0.f, 0.f, 0.f, 0.f};
            int e = s0;
            for (; e + 4 <= s1; e += 4) {
                int a0 = oL[e], a1 = oL[e + 1], a2 = oL[e + 2], a3 = oL[e + 3];
                uint4 v0 = *reinterpret_cast<const uint4*>(hwb + (size_t)a0 * NDIM + c8 * 8);
                uint4 v1 = *reinterpret_cast<const uint4*>(hwb + (size_t)a1 * NDIM + c8 * 8);
                uint4 v2 = *reinterpret_cast<const uint4*>(hwb + (size_t)a2 * NDIM + c8 * 8);
                uint4 v3 = *reinterpret_cast<const uint4*>(hwb + (size_t)a3 * NDIM + c8 * 8);
                ACCV(acc, v0); ACCV(acc2, v1); ACCV(acc, v2); ACCV(acc2, v3);
            }
            for (; e < s1; ++e) {
                int a0 = oL[e];
                uint4 v0 = *reinterpret_cast<const uint4*>(hwb + (size_t)a0 * NDIM + c8 * 8);
                ACCV(acc, v0);
            }
            const float nv = norm[gnode];
            float4 o0, o1;
            o0.x = fmaxf((acc[0] + acc2[0]) * nv, 0.f);
            o0.y = fmaxf((acc[1] + acc2[1]) * nv, 0.f);
            o0.z = fmaxf((acc[2] + acc2[2]) * nv, 0.f);
            o0.w = fmaxf((acc[3] + acc2[3]) * nv, 0.f);
            o1.x = fmaxf((acc[4] + acc2[4]) * nv, 0.f);
            o1.y = fmaxf((acc[5] + acc2[5]) * nv, 0.f);
            o1.z = fmaxf((acc[6] + acc2[6]) * nv, 0.f);
            o1.w = fmaxf((acc[7] + acc2[7]) * nv, 0.f);
            float4* po = reinterpret_cast<float4*>(out + (size_t)gnode * NDIM + c8 * 8);
            po[0] = o0; po[1] = o1;
        }
    }
}

extern "C" void kernel_launch(void* const* d_in, const int* in_sizes, int n_in,
                              void* d_out, int out_size, void* d_ws, size_t ws_size,
                              hipStream_t stream)
{
    const float* h    = (const float*)d_in[0];
    const float* norm = (const float*)d_in[1];
    const float* w    = (const float*)d_in[2];
    const int*   src  = (const int*)d_in[3];
    const int*   dst  = (const int*)d_in[4];
    float* out = (float*)d_out;

    // workspace layout
    unsigned short* hwb = (unsigned short*)d_ws;        // 50000*96 bf16 = 9.6 MB
    unsigned short* wt  = hwb + (size_t)M_NODES * NDIM; // 96*256 bf16 = 48 KB
    int* gcursor = (int*)(wt + KDIM * NDIM);            // 782 (+pad)
    unsigned* binned = (unsigned*)(gcursor + 800);      // 782*1536 = 4.8 MB

    prep_w_kernel<<<(KDIM * NDIM + 255) / 256, 256, 0, stream>>>(w, wt, gcursor);
    fused_gemm_scatter_kernel<<<GEMM_BLKS + NBLK_SC, 256, 0, stream>>>(
        h, norm, wt, hwb, src, dst, gcursor, binned);
    csr_agg_kernel<<<NBUCK, 256, 0, stream>>>(binned, gcursor, hwb, norm, out);
}

// Round 12
// 70.550 us; speedup vs baseline: 1.1482x; 1.1482x over previous
//
#include <hip/hip_runtime.h>

#define M_NODES 50000
#define KDIM    256
#define NDIM    96
#define NEDGE   800000
#define BM      64     // gemm rows per block
#define GEMM_BLKS 782  // ceil(50000/64)
#define NPB     64     // nodes per bucket
#define NBUCK   782    // ceil(50000/64)
#define CAPB    1536   // per-bucket edge capacity (mean 1023, sigma 32 -> +16s)
#define EPB     2048   // edges per scatter block
#define NBLK_SC 391    // ceil(800000/2048)
#define CONV_BLKS 6250 // 12.8M h-elems / 2048 per block
#define WT_BLKS 96

typedef short bf16x8 __attribute__((ext_vector_type(8)));   // 8 bf16 (4 VGPRs)
typedef float f32x4  __attribute__((ext_vector_type(4)));

// round-to-nearest-even f32 -> bf16 (as u16)
__device__ inline unsigned short f2bf(float x) {
    unsigned u = __float_as_uint(x);
    u = (u + 0x7fffu + ((u >> 16) & 1u)) >> 16;
    return (unsigned short)u;
}
__device__ inline unsigned pack2bf(float x, float y) {
    return (unsigned)f2bf(x) | ((unsigned)f2bf(y) << 16);
}

// async 16B global -> LDS (DMA, no VGPR round-trip). dst: wave-uniform base,
// each lane lands at base + lane*16. src: per-lane address.
__device__ inline void gload_lds16(const void* g, void* l) {
    __builtin_amdgcn_global_load_lds(
        (const __attribute__((address_space(1))) void*)g,
        (__attribute__((address_space(3))) void*)l, 16, 0, 0);
}

// -------- Kernel 0: prep -----------------------------------------------
// blocks [0,6250): hb = bf16(h), PRE-SWIZZLED rows (chunk ^= (row&7)<<4)
// blocks [6250,6346): wt[n][k] = bf16(w[k][n])
// block 6346: init gcursor
__global__ __launch_bounds__(256) void prep_kernel(
    const float* __restrict__ h, const float* __restrict__ w,
    unsigned short* __restrict__ hb, unsigned short* __restrict__ wt,
    int* __restrict__ gcursor)
{
    const int b = blockIdx.x, t = threadIdx.x;
    if (b < CONV_BLKS) {
        const int idx8 = b * 256 + t;       // 8-elem unit
        const int row  = idx8 >> 5;         // 32 units per 256-elem row
        const int u    = idx8 & 31;
        const float* hp = h + (size_t)row * KDIM + u * 8;
        float4 p = *reinterpret_cast<const float4*>(hp);
        float4 q = *reinterpret_cast<const float4*>(hp + 4);
        uint4 o;
        o.x = pack2bf(p.x, p.y); o.y = pack2bf(p.z, p.w);
        o.z = pack2bf(q.x, q.y); o.w = pack2bf(q.z, q.w);
        char* dst = reinterpret_cast<char*>(hb) + (size_t)row * 512
                  + ((u * 16) ^ ((row & 7) << 4));
        *reinterpret_cast<uint4*>(dst) = o;
    } else if (b < CONV_BLKS + WT_BLKS) {
        const int n = b - CONV_BLKS;        // 0..95
        wt[n * 256 + t] = f2bf(w[(size_t)t * NDIM + n]);
    } else {
        for (int i = t; i < NBUCK; i += 256) gcursor[i] = i * CAPB;
    }
}

// -------- Kernel 1 (fat): gemm blocks [0,782) + scatter [782,1173) -----
// GEMM: W in swizzled LDS (48KB); A-tile (64 rows x 512B bf16, swizzled
//   content) staged via 8x async global_load_lds width-16 per thread.
//   One barrier; MFMA reads both operands from LDS conflict-free.
// SCATTER: bucket=dst>>6; LDS count -> chunk reserve -> packed write.
__global__ __launch_bounds__(256) void fused_gemm_scatter_kernel(
    const unsigned short* __restrict__ hb, const float* __restrict__ norm,
    const unsigned short* __restrict__ wt, unsigned short* __restrict__ hwb,
    const int* __restrict__ src, const int* __restrict__ dst,
    int* __restrict__ gcursor, unsigned* __restrict__ binned)
{
    __shared__ __align__(16) char smem[81920];   // [0,48K) W, [48K,80K) A

    const int tid = threadIdx.x;

    if (blockIdx.x < GEMM_BLKS) {
        // ---------------- GEMM path ----------------
        char* w_lds = smem;
        char* a_lds = smem + 49152;
        const int lane = tid & 63;
        const int wv   = tid >> 6;                   // 0..3
        const int row0 = blockIdx.x * BM;

        // issue A-tile DMA first: wave wv owns bytes [wv*8K, +8K)
        const char* asrc = reinterpret_cast<const char*>(hb) + (size_t)row0 * 512;
#pragma unroll
        for (int it = 0; it < 8; ++it) {
            const int boff = wv * 8192 + it * 1024;
            gload_lds16(asrc + boff + lane * 16, a_lds + boff);
        }

        // stage Wt -> w_lds (swizzled), 12 x 16B per thread
#pragma unroll
        for (int it = 0; it < 12; ++it) {
            int idx = tid + it * 256;                // 0..3071
            int n   = idx >> 5;                      // 0..95
            int kb  = (idx & 31) * 16;               // byte in row
            uint4 v = *reinterpret_cast<const uint4*>(
                reinterpret_cast<const char*>(wt) + n * 512 + kb);
            *reinterpret_cast<uint4*>(w_lds + n * 512 + (kb ^ ((n & 7) << 4))) = v;
        }
        __syncthreads();   // drains vmcnt (DMA) + lgkm (ds_write)

        f32x4 acc[6];
#pragma unroll
        for (int f = 0; f < 6; ++f) acc[f] = (f32x4){0.f, 0.f, 0.f, 0.f};

        const int ar = wv * 16 + (lane & 15);        // A row (local)
        const int kg = lane >> 4;                    // 0..3

#pragma unroll
        for (int s = 0; s < 8; ++s) {
            const int kb = s * 64 + kg * 16;         // byte offset of k-slice
            bf16x8 a = *reinterpret_cast<const bf16x8*>(
                a_lds + ar * 512 + (kb ^ ((ar & 7) << 4)));
#pragma unroll
            for (int f = 0; f < 6; ++f) {
                int n = f * 16 + (lane & 15);
                bf16x8 b = *reinterpret_cast<const bf16x8*>(
                    w_lds + n * 512 + (kb ^ ((n & 7) << 4)));
                acc[f] = __builtin_amdgcn_mfma_f32_16x16x32_bf16(a, b, acc[f], 0, 0, 0);
            }
        }

        // epilogue: C/D layout col=lane&15, row=(lane>>4)*4+reg
        const int crow = wv * 16 + (lane >> 4) * 4;
        const int ccol = lane & 15;
#pragma unroll
        for (int r = 0; r < 4; ++r) {
            int row = row0 + crow + r;
            if (row < M_NODES) {
                float nv = norm[row];
#pragma unroll
                for (int f = 0; f < 6; ++f)
                    hwb[(size_t)row * NDIM + f * 16 + ccol] = f2bf(acc[f][r] * nv);
            }
        }
    } else {
        // ---------------- SCATTER path ----------------
        int* s_cnt  = reinterpret_cast<int*>(smem);
        int* s_base = s_cnt + NBUCK;
        const int blk = blockIdx.x - GEMM_BLKS;
        const int e0 = blk * EPB;
        const int e1 = (e0 + EPB < NEDGE) ? e0 + EPB : NEDGE;

        for (int i = tid; i < NBUCK; i += 256) s_cnt[i] = 0;
        __syncthreads();
        for (int e = e0 + tid; e < e1; e += 256)
            atomicAdd(&s_cnt[dst[e] >> 6], 1);
        __syncthreads();
        for (int i = tid; i < NBUCK; i += 256) {
            int c = s_cnt[i];
            s_base[i] = c ? atomicAdd(&gcursor[i], c) : 0;
        }
        __syncthreads();
        for (int i = tid; i < NBUCK; i += 256) s_cnt[i] = 0;  // reuse as cursor
        __syncthreads();
        for (int e = e0 + tid; e < e1; e += 256) {
            int d = dst[e];
            int b = d >> 6;
            int pos = s_base[b] + atomicAdd(&s_cnt[b], 1);
            if (pos < (b + 1) * CAPB)                          // overflow guard
                binned[pos] = ((unsigned)(d & 63) << 16) | (unsigned)src[e];
        }
    }
}

// -------- Kernel 2: fused per-bucket CSR build + segment sum + relu ----
#define ACCV(A, v)                                     \
    A[0] += __uint_as_float((v).x << 16);              \
    A[1] += __uint_as_float((v).x & 0xffff0000u);      \
    A[2] += __uint_as_float((v).y << 16);              \
    A[3] += __uint_as_float((v).y & 0xffff0000u);      \
    A[4] += __uint_as_float((v).z << 16);              \
    A[5] += __uint_as_float((v).z & 0xffff0000u);      \
    A[6] += __uint_as_float((v).w << 16);              \
    A[7] += __uint_as_float((v).w & 0xffff0000u);

__global__ __launch_bounds__(256) void csr_agg_kernel(
    const unsigned* __restrict__ binned, const int* __restrict__ gcursor,
    const unsigned short* __restrict__ hwb, const float* __restrict__ norm,
    float* __restrict__ out)
{
    __shared__ unsigned eL[CAPB];          // raw packed edges (6 KB)
    __shared__ unsigned short oL[CAPB];    // node-ordered src ids (3 KB)
    __shared__ int cnt[NPB];               // histogram / cursor / end
    __shared__ int pfxE[NPB];              // exclusive start

    const int b  = blockIdx.x;
    const int t  = threadIdx.x;
    const int e0 = b * CAPB;
    int cntE = gcursor[b] - e0;
    if (cntE > CAPB) cntE = CAPB;

    for (int i = t; i < cntE; i += 256) eL[i] = binned[e0 + i];
    if (t < NPB) cnt[t] = 0;
    __syncthreads();
    for (int i = t; i < cntE; i += 256)
        atomicAdd(&cnt[(eL[i] >> 16) & 63], 1);
    __syncthreads();
    if (t < NPB) {                         // wave-0 barrier-free 64-wide scan
        int v = cnt[t];
        int x = v;
#pragma unroll
        for (int st = 1; st < 64; st <<= 1) {
            int o = __shfl_up(x, st, 64);
            if (t >= st) x += o;
        }
        int ex = x - v;                    // exclusive
        pfxE[t] = ex;
        cnt[t]  = ex;                      // cursor
    }
    __syncthreads();
    for (int i = t; i < cntE; i += 256) {
        unsigned v = eL[i];
        int d = (v >> 16) & 63;
        int p = atomicAdd(&cnt[d], 1);
        oL[p] = (unsigned short)(v & 0xffffu);
    }
    __syncthreads();
    // cnt[node] == segment end; pfxE[node] == segment start.

    // aggregate: 64 nodes x 12 channel-groups = 768 units, 3 passes
#pragma unroll
    for (int pass = 0; pass < 3; ++pass) {
        const int u     = pass * 256 + t;
        const int node  = u / 12;
        const int c8    = u - node * 12;       // channels c8*8 .. +7
        const int gnode = b * NPB + node;
        if (gnode < M_NODES) {
            const int s0 = pfxE[node];
            const int s1 = cnt[node];
            float acc[8]  = {0.f, 0.f, 0.f, 0.f, 0.f, 0.f, 0.f, 0.f};
            float acc2[8] = {0.f, 0.f, 0.f, 0.f, 0.f, 0.f, 0.f, 0.f};
            int e = s0;
            for (; e + 4 <= s1; e += 4) {
                int a0 = oL[e], a1 = oL[e + 1], a2 = oL[e + 2], a3 = oL[e + 3];
                uint4 v0 = *reinterpret_cast<const uint4*>(hwb + (size_t)a0 * NDIM + c8 * 8);
                uint4 v1 = *reinterpret_cast<const uint4*>(hwb + (size_t)a1 * NDIM + c8 * 8);
                uint4 v2 = *reinterpret_cast<const uint4*>(hwb + (size_t)a2 * NDIM + c8 * 8);
                uint4 v3 = *reinterpret_cast<const uint4*>(hwb + (size_t)a3 * NDIM + c8 * 8);
                ACCV(acc, v0); ACCV(acc2, v1); ACCV(acc, v2); ACCV(acc2, v3);
            }
            for (; e < s1; ++e) {
                int a0 = oL[e];
                uint4 v0 = *reinterpret_cast<const uint4*>(hwb + (size_t)a0 * NDIM + c8 * 8);
                ACCV(acc, v0);
            }
            const float nv = norm[gnode];
            float4 o0, o1;
            o0.x = fmaxf((acc[0] + acc2[0]) * nv, 0.f);
            o0.y = fmaxf((acc[1] + acc2[1]) * nv, 0.f);
            o0.z = fmaxf((acc[2] + acc2[2]) * nv, 0.f);
            o0.w = fmaxf((acc[3] + acc2[3]) * nv, 0.f);
            o1.x = fmaxf((acc[4] + acc2[4]) * nv, 0.f);
            o1.y = fmaxf((acc[5] + acc2[5]) * nv, 0.f);
            o1.z = fmaxf((acc[6] + acc2[6]) * nv, 0.f);
            o1.w = fmaxf((acc[7] + acc2[7]) * nv, 0.f);
            float4* po = reinterpret_cast<float4*>(out + (size_t)gnode * NDIM + c8 * 8);
            po[0] = o0; po[1] = o1;
        }
    }
}

extern "C" void kernel_launch(void* const* d_in, const int* in_sizes, int n_in,
                              void* d_out, int out_size, void* d_ws, size_t ws_size,
                              hipStream_t stream)
{
    const float* h    = (const float*)d_in[0];
    const float* norm = (const float*)d_in[1];
    const float* w    = (const float*)d_in[2];
    const int*   src  = (const int*)d_in[3];
    const int*   dst  = (const int*)d_in[4];
    float* out = (float*)d_out;

    // workspace layout (hb NOT last: gemm tail block over-reads 24KB past hb)
    unsigned short* hwb = (unsigned short*)d_ws;        // 50000*96 bf16 = 9.6 MB
    unsigned short* wt  = hwb + (size_t)M_NODES * NDIM; // 96*256 bf16 = 48 KB
    int* gcursor = (int*)(wt + KDIM * NDIM);            // 782 (+pad)
    unsigned short* hb = (unsigned short*)(gcursor + 800); // 50000*256 bf16 = 25.6 MB
    unsigned* binned = (unsigned*)(hb + (size_t)M_NODES * KDIM); // 4.8 MB

    prep_kernel<<<CONV_BLKS + WT_BLKS + 1, 256, 0, stream>>>(h, w, hb, wt, gcursor);
    fused_gemm_scatter_kernel<<<GEMM_BLKS + NBLK_SC, 256, 0, stream>>>(
        hb, norm, wt, hwb, src, dst, gcursor, binned);
    csr_agg_kernel<<<NBUCK, 256, 0, stream>>>(binned, gcursor, hwb, norm, out);
}

// Round 13
// 63.916 us; speedup vs baseline: 1.2674x; 1.1038x over previous
//
#include <hip/hip_runtime.h>

#define M_NODES 50000
#define KDIM    256
#define NDIM    96
#define NEDGE   800000
#define BM      64     // gemm rows per block
#define GEMM_BLKS 782  // ceil(50000/64)
#define NPB     64     // nodes per bucket
#define NBUCK   782    // ceil(50000/64)
#define CAPB    1536   // per-bucket edge capacity (mean 1023, sigma 32 -> +16s)
#define EPB     2048   // edges per scatter block
#define NBLK_SC 391    // ceil(800000/2048)
#define TOT_BLKS (GEMM_BLKS + NBLK_SC)   // 1173

typedef short bf16x8 __attribute__((ext_vector_type(8)));   // 8 bf16 (4 VGPRs)
typedef float f32x4  __attribute__((ext_vector_type(4)));

// round-to-nearest-even f32 -> bf16 (as u16)
__device__ inline unsigned short f2bf(float x) {
    unsigned u = __float_as_uint(x);
    u = (u + 0x7fffu + ((u >> 16) & 1u)) >> 16;
    return (unsigned short)u;
}
__device__ inline unsigned pack2bf(float x, float y) {
    return (unsigned)f2bf(x) | ((unsigned)f2bf(y) << 16);
}

// -------- Kernel 0: wt[n][k] = bf16(w[k][n]); block 96 inits gcursor ---
__global__ __launch_bounds__(256) void prep_w_kernel(
    const float* __restrict__ w, unsigned short* __restrict__ wt,
    int* __restrict__ gcursor)
{
    const int b = blockIdx.x, t = threadIdx.x;
    if (b < 96) {
        wt[b * 256 + t] = f2bf(w[(size_t)t * NDIM + b]);
    } else {
        for (int i = t; i < NBUCK; i += 256) gcursor[i] = i * CAPB;
    }
}

// -------- Kernel 1 (fat, interleaved): gemm + scatter ------------------
// blockIdx%3==2 -> scatter block (id/3); else gemm (id - (id+1)/3).
// Interleaving co-schedules both types so scatter's latency-bound LDS
// atomics hide under gemm's HBM streaming.
// GEMM: A staged f32->bf16->swizzled LDS inline (16 indep iters, compiler
//   pipelines); W in swizzled LDS; one barrier; conflict-free MFMA reads.
// SCATTER: bucket=dst>>6; LDS count -> chunk reserve -> packed write.
__global__ __launch_bounds__(256) void fused_gemm_scatter_kernel(
    const float* __restrict__ h, const float* __restrict__ norm,
    const unsigned short* __restrict__ wt, unsigned short* __restrict__ hwb,
    const int* __restrict__ src, const int* __restrict__ dst,
    int* __restrict__ gcursor, unsigned* __restrict__ binned)
{
    __shared__ __align__(16) char smem[81920];   // [0,48K) W, [48K,80K) A

    const int tid = threadIdx.x;
    const unsigned bx = blockIdx.x;

    if (bx % 3 != 2) {
        // ---------------- GEMM path ----------------
        const int gid = (int)bx - (int)((bx + 1) / 3);   // 0..781
        char* w_lds = smem;
        char* a_lds = smem + 49152;
        const int lane = tid & 63;
        const int wv   = tid >> 6;                   // 0..3
        const int row0 = gid * BM;

        // stage A: h f32 -> bf16, swizzled; 16 x (16B load -> 8B write)
#pragma unroll
        for (int it = 0; it < 16; ++it) {
            int idx = tid + it * 256;                // 0..4095
            int r   = idx >> 6;                      // 0..63
            int c4  = idx & 63;                      // float4 within row
            int row = row0 + r;
            if (row >= M_NODES) row = M_NODES - 1;   // safe clamp
            float4 v = *reinterpret_cast<const float4*>(h + (size_t)row * KDIM + c4 * 4);
            uint2 p = make_uint2(pack2bf(v.x, v.y), pack2bf(v.z, v.w));
            *reinterpret_cast<uint2*>(a_lds + r * 512 + ((c4 * 8) ^ ((r & 7) << 4))) = p;
        }
        // stage Wt -> w_lds (swizzled), 12 x 16B per thread
#pragma unroll
        for (int it = 0; it < 12; ++it) {
            int idx = tid + it * 256;                // 0..3071
            int n   = idx >> 5;                      // 0..95
            int kb  = (idx & 31) * 16;               // byte in row
            uint4 v = *reinterpret_cast<const uint4*>(
                reinterpret_cast<const char*>(wt) + n * 512 + kb);
            *reinterpret_cast<uint4*>(w_lds + n * 512 + (kb ^ ((n & 7) << 4))) = v;
        }
        __syncthreads();

        f32x4 acc[6];
#pragma unroll
        for (int f = 0; f < 6; ++f) acc[f] = (f32x4){0.f, 0.f, 0.f, 0.f};

        const int ar = wv * 16 + (lane & 15);        // A row (local)
        const int kg = lane >> 4;                    // 0..3

#pragma unroll
        for (int s = 0; s < 8; ++s) {
            const int kb = s * 64 + kg * 16;         // byte offset of k-slice
            bf16x8 a = *reinterpret_cast<const bf16x8*>(
                a_lds + ar * 512 + (kb ^ ((ar & 7) << 4)));
#pragma unroll
            for (int f = 0; f < 6; ++f) {
                int n = f * 16 + (lane & 15);
                bf16x8 b = *reinterpret_cast<const bf16x8*>(
                    w_lds + n * 512 + (kb ^ ((n & 7) << 4)));
                acc[f] = __builtin_amdgcn_mfma_f32_16x16x32_bf16(a, b, acc[f], 0, 0, 0);
            }
        }

        // epilogue: C/D layout col=lane&15, row=(lane>>4)*4+reg
        const int crow = wv * 16 + (lane >> 4) * 4;
        const int ccol = lane & 15;
#pragma unroll
        for (int r = 0; r < 4; ++r) {
            int row = row0 + crow + r;
            if (row < M_NODES) {
                float nv = norm[row];
#pragma unroll
                for (int f = 0; f < 6; ++f)
                    hwb[(size_t)row * NDIM + f * 16 + ccol] = f2bf(acc[f][r] * nv);
            }
        }
    } else {
        // ---------------- SCATTER path ----------------
        int* s_cnt  = reinterpret_cast<int*>(smem);
        int* s_base = s_cnt + NBUCK;
        const int blk = (int)(bx / 3);               // 0..390
        const int e0 = blk * EPB;
        const int e1 = (e0 + EPB < NEDGE) ? e0 + EPB : NEDGE;

        for (int i = tid; i < NBUCK; i += 256) s_cnt[i] = 0;
        __syncthreads();
        for (int e = e0 + tid; e < e1; e += 256)
            atomicAdd(&s_cnt[dst[e] >> 6], 1);
        __syncthreads();
        for (int i = tid; i < NBUCK; i += 256) {
            int c = s_cnt[i];
            s_base[i] = c ? atomicAdd(&gcursor[i], c) : 0;
        }
        __syncthreads();
        for (int i = tid; i < NBUCK; i += 256) s_cnt[i] = 0;  // reuse as cursor
        __syncthreads();
        for (int e = e0 + tid; e < e1; e += 256) {
            int d = dst[e];
            int b = d >> 6;
            int pos = s_base[b] + atomicAdd(&s_cnt[b], 1);
            if (pos < (b + 1) * CAPB)                          // overflow guard
                binned[pos] = ((unsigned)(d & 63) << 16) | (unsigned)src[e];
        }
    }
}

// -------- Kernel 2: fused per-bucket CSR build + segment sum + relu ----
#define ACCV(A, v)                                     \
    A[0] += __uint_as_float((v).x << 16);              \
    A[1] += __uint_as_float((v).x & 0xffff0000u);      \
    A[2] += __uint_as_float((v).y << 16);              \
    A[3] += __uint_as_float((v).y & 0xffff0000u);      \
    A[4] += __uint_as_float((v).z << 16);              \
    A[5] += __uint_as_float((v).z & 0xffff0000u);      \
    A[6] += __uint_as_float((v).w << 16);              \
    A[7] += __uint_as_float((v).w & 0xffff0000u);

__global__ __launch_bounds__(256) void csr_agg_kernel(
    const unsigned* __restrict__ binned, const int* __restrict__ gcursor,
    const unsigned short* __restrict__ hwb, const float* __restrict__ norm,
    float* __restrict__ out)
{
    __shared__ unsigned eL[CAPB];          // raw packed edges (6 KB)
    __shared__ unsigned short oL[CAPB];    // node-ordered src ids (3 KB)
    __shared__ int cnt[NPB];               // histogram / cursor / end
    __shared__ int pfxE[NPB];              // exclusive start

    const int b  = blockIdx.x;
    const int t  = threadIdx.x;
    const int e0 = b * CAPB;
    int cntE = gcursor[b] - e0;
    if (cntE > CAPB) cntE = CAPB;

    for (int i = t; i < cntE; i += 256) eL[i] = binned[e0 + i];
    if (t < NPB) cnt[t] = 0;
    __syncthreads();
    for (int i = t; i < cntE; i += 256)
        atomicAdd(&cnt[(eL[i] >> 16) & 63], 1);
    __syncthreads();
    if (t < NPB) {                         // wave-0 barrier-free 64-wide scan
        int v = cnt[t];
        int x = v;
#pragma unroll
        for (int st = 1; st < 64; st <<= 1) {
            int o = __shfl_up(x, st, 64);
            if (t >= st) x += o;
        }
        int ex = x - v;                    // exclusive
        pfxE[t] = ex;
        cnt[t]  = ex;                      // cursor
    }
    __syncthreads();
    for (int i = t; i < cntE; i += 256) {
        unsigned v = eL[i];
        int d = (v >> 16) & 63;
        int p = atomicAdd(&cnt[d], 1);
        oL[p] = (unsigned short)(v & 0xffffu);
    }
    __syncthreads();
    // cnt[node] == segment end; pfxE[node] == segment start.

    // aggregate: 64 nodes x 12 channel-groups = 768 units, 3 passes
#pragma unroll
    for (int pass = 0; pass < 3; ++pass) {
        const int u     = pass * 256 + t;
        const int node  = u / 12;
        const int c8    = u - node * 12;       // channels c8*8 .. +7
        const int gnode = b * NPB + node;
        if (gnode < M_NODES) {
            const int s0 = pfxE[node];
            const int s1 = cnt[node];
            float acc[8]  = {0.f, 0.f, 0.f, 0.f, 0.f, 0.f, 0.f, 0.f};
            float acc2[8] = {0.f, 0.f, 0.f, 0.f, 0.f, 0.f, 0.f, 0.f};
            int e = s0;
            for (; e + 4 <= s1; e += 4) {
                int a0 = oL[e], a1 = oL[e + 1], a2 = oL[e + 2], a3 = oL[e + 3];
                uint4 v0 = *reinterpret_cast<const uint4*>(hwb + (size_t)a0 * NDIM + c8 * 8);
                uint4 v1 = *reinterpret_cast<const uint4*>(hwb + (size_t)a1 * NDIM + c8 * 8);
                uint4 v2 = *reinterpret_cast<const uint4*>(hwb + (size_t)a2 * NDIM + c8 * 8);
                uint4 v3 = *reinterpret_cast<const uint4*>(hwb + (size_t)a3 * NDIM + c8 * 8);
                ACCV(acc, v0); ACCV(acc2, v1); ACCV(acc, v2); ACCV(acc2, v3);
            }
            for (; e < s1; ++e) {
                int a0 = oL[e];
                uint4 v0 = *reinterpret_cast<const uint4*>(hwb + (size_t)a0 * NDIM + c8 * 8);
                ACCV(acc, v0);
            }
            const float nv = norm[gnode];
            float4 o0, o1;
            o0.x = fmaxf((acc[0] + acc2[0]) * nv, 0.f);
            o0.y = fmaxf((acc[1] + acc2[1]) * nv, 0.f);
            o0.z = fmaxf((acc[2] + acc2[2]) * nv, 0.f);
            o0.w = fmaxf((acc[3] + acc2[3]) * nv, 0.f);
            o1.x = fmaxf((acc[4] + acc2[4]) * nv, 0.f);
            o1.y = fmaxf((acc[5] + acc2[5]) * nv, 0.f);
            o1.z = fmaxf((acc[6] + acc2[6]) * nv, 0.f);
            o1.w = fmaxf((acc[7] + acc2[7]) * nv, 0.f);
            float4* po = reinterpret_cast<float4*>(out + (size_t)gnode * NDIM + c8 * 8);
            po[0] = o0; po[1] = o1;
        }
    }
}

extern "C" void kernel_launch(void* const* d_in, const int* in_sizes, int n_in,
                              void* d_out, int out_size, void* d_ws, size_t ws_size,
                              hipStream_t stream)
{
    const float* h    = (const float*)d_in[0];
    const float* norm = (const float*)d_in[1];
    const float* w    = (const float*)d_in[2];
    const int*   src  = (const int*)d_in[3];
    const int*   dst  = (const int*)d_in[4];
    float* out = (float*)d_out;

    // workspace layout
    unsigned short* hwb = (unsigned short*)d_ws;        // 50000*96 bf16 = 9.6 MB
    unsigned short* wt  = hwb + (size_t)M_NODES * NDIM; // 96*256 bf16 = 48 KB
    int* gcursor = (int*)(wt + KDIM * NDIM);            // 782 (+pad)
    unsigned* binned = (unsigned*)(gcursor + 800);      // 782*1536 = 4.8 MB

    prep_w_kernel<<<97, 256, 0, stream>>>(w, wt, gcursor);
    fused_gemm_scatter_kernel<<<TOT_BLKS, 256, 0, stream>>>(
        h, norm, wt, hwb, src, dst, gcursor, binned);
    csr_agg_kernel<<<NBUCK, 256, 0, stream>>>(binned, gcursor, hwb, norm, out);
}